// Round 13
// baseline (1576.403 us; speedup 1.0000x reference)
//
#include <hip/hip_runtime.h>
#include <hip/hip_cooperative_groups.h>
#include <cstdint>

namespace cg = cooperative_groups;

#define BSZ 512
#define NG 5
#define NEL 32
#define IN_C 5
#define HC 64
#define NN (BSZ * NG * NEL)   // 81920 nodes
#define NE (NN * 16)          // 1310720 edges
#define NC 3
#define KTOT (NG * NEL * HC)  // 10240
#define NSLICE 32
#define NGR (NN / 16)         // 5120 node groups
#define NCB 320               // coarse buckets (256 nodes each, dst>>8)
#define CCHUNK (NE / NCB)     // 4096 edges per build block
#define SORTCAP 5120

typedef __attribute__((ext_vector_type(8))) short bf16x8;
typedef __attribute__((ext_vector_type(4))) float f32x4;

__device__ __forceinline__ float bcast(float v, int l) {
  return __int_as_float(__builtin_amdgcn_readlane(__float_as_int(v), l));
}

__device__ __forceinline__ ushort bf16r(float f) {   // RNE f32->bf16
  unsigned u = __float_as_uint(f);
  return (ushort)((u + 0x7FFFu + ((u >> 16) & 1u)) >> 16);
}

__device__ __forceinline__ float bf16f(ushort s) {
  return __uint_as_float(((unsigned)s) << 16);
}

__device__ __forceinline__ float sigmoidf_(float x) {
  return 1.0f / (1.0f + __expf(-x));
}

__device__ __forceinline__ float tanhf_(float x) {
  x = fminf(fmaxf(x, -15.0f), 15.0f);
  float e = __expf(2.0f * x);
  return (e - 1.0f) / (e + 1.0f);
}

// ---------------- build kernels (proven R11 versions) ----------------
__global__ void __launch_bounds__(256) k_chist(const int* __restrict__ ei,
                                               int* __restrict__ ghist) {
  __shared__ int lh[NCB];
  const int t = threadIdx.x;
  for (int i = t; i < NCB; i += 256) lh[i] = 0;
  __syncthreads();
  const int base = blockIdx.x * CCHUNK;
  for (int k = t; k < CCHUNK; k += 256)
    atomicAdd(&lh[ei[NE + base + k] >> 8], 1);
  __syncthreads();
  for (int i = t; i < NCB; i += 256) ghist[i * NCB + blockIdx.x] = lh[i];
}

__global__ void __launch_bounds__(NCB) k_rowscan(const int* __restrict__ ghist,
                                                 int* __restrict__ gof,
                                                 int* __restrict__ tot) {
  __shared__ int part[NCB];
  const int t = threadIdx.x;
  const int b = blockIdx.x;
  const int v = ghist[b * NCB + t];
  part[t] = v;
  __syncthreads();
  for (int d = 1; d < NCB; d <<= 1) {
    int x = (t >= d) ? part[t - d] : 0;
    __syncthreads();
    part[t] += x;
    __syncthreads();
  }
  gof[b * NCB + t] = part[t] - v;
  if (t == NCB - 1) tot[b] = part[t];
}

__global__ void __launch_bounds__(NCB) k_cscan2(const int* __restrict__ tot,
                                                int* __restrict__ cstart) {
  __shared__ int part[NCB];
  const int t = threadIdx.x;
  const int v = tot[t];
  part[t] = v;
  __syncthreads();
  for (int d = 1; d < NCB; d <<= 1) {
    int x = (t >= d) ? part[t - d] : 0;
    __syncthreads();
    part[t] += x;
    __syncthreads();
  }
  cstart[t] = part[t] - v;
  if (t == NCB - 1) cstart[NCB] = part[t];
}

__global__ void __launch_bounds__(256) k_cpart(const int* __restrict__ ei,
                                               const float* __restrict__ ea,
                                               const int* __restrict__ gof,
                                               const int* __restrict__ cstart,
                                               int* __restrict__ ent4,
                                               unsigned char* __restrict__ dstlo) {
  __shared__ int cur[NCB];
  const int t = threadIdx.x;
  for (int i = t; i < NCB; i += 256)
    cur[i] = gof[i * NCB + blockIdx.x] + cstart[i];
  __syncthreads();
  const int base = blockIdx.x * CCHUNK;
  for (int k = t; k < CCHUNK; k += 256) {
    int e = base + k;
    int src = ei[e];
    int dst = ei[NE + e];
    ushort bw = bf16r(ea[e]);       // w in [0,1): bit15==0, fits bits 17..31
    int slot = atomicAdd(&cur[dst >> 8], 1);
    ent4[slot] = src | ((int)bw << 17);
    dstlo[slot] = (unsigned char)(dst & 255);
  }
}

__global__ void __launch_bounds__(256) k_sort(const int* __restrict__ ent4,
                                              const unsigned char* __restrict__ dstlo,
                                              const int* __restrict__ cstart,
                                              int* __restrict__ csr4,
                                              int* __restrict__ off,
                                              int* __restrict__ cnt) {
  __shared__ int nh[256];
  __shared__ int part[256];
  __shared__ int sent[SORTCAP];
  const int t = threadIdx.x;
  const int b = blockIdx.x;
  const int r0 = cstart[b];
  const int r1 = cstart[b + 1];
  int len = r1 - r0;
  if (len > SORTCAP) len = SORTCAP;
  nh[t] = 0;
  __syncthreads();
  for (int k = t; k < len; k += 256) atomicAdd(&nh[dstlo[r0 + k]], 1);
  __syncthreads();
  int a0 = nh[t];
  part[t] = a0;
  __syncthreads();
  for (int d = 1; d < 256; d <<= 1) {
    int x = (t >= d) ? part[t - d] : 0;
    __syncthreads();
    part[t] += x;
    __syncthreads();
  }
  const int base = part[t] - a0;
  const int n0 = b * 256;
  off[n0 + t] = r0 + base;
  cnt[n0 + t] = a0;
  nh[t] = base;
  __syncthreads();
  for (int k = t; k < len; k += 256) {
    int d = dstlo[r0 + k];
    int slot = atomicAdd(&nh[d], 1);
    sent[slot] = ent4[r0 + k];
  }
  __syncthreads();
  for (int k = t; k < len; k += 256) csr4[r0 + k] = sent[k];
}

__global__ void k_cvtw(const float* __restrict__ W1, ushort* __restrict__ w1b) {
  int i = blockIdx.x * 256 + threadIdx.x;
  w1b[i] = bf16r(W1[i]);
}

// =============== fused main: init + [gemm|aggr|gru]x2 + mlp1 + tail ==========
// Grid-stride safe for ANY grid size (host clamps to cooperative capacity).
__global__ void __launch_bounds__(256, 4) k_main(
    ushort* __restrict__ hb, ushort* __restrict__ m16,
    ushort* __restrict__ aggr16, const float* __restrict__ x,
    const int* __restrict__ off, const int* __restrict__ cnt,
    const int* __restrict__ csr4,
    const float* __restrict__ Wg, const float* __restrict__ wih,
    const float* __restrict__ whh, const float* __restrict__ bih,
    const float* __restrict__ bhh, const ushort* __restrict__ w1b,
    float* __restrict__ part, const float* __restrict__ b1,
    const float* __restrict__ W2, const float* __restrict__ b2,
    const float* __restrict__ W3, const float* __restrict__ b3,
    const float* __restrict__ W4, const float* __restrict__ b4,
    float* __restrict__ out) {
  cg::grid_group grid = cg::this_grid();
  const int t = threadIdx.x;
  const int lane = t & 63;
  const int w = t >> 6;
  const int cl = lane & 15;
  const int quad = lane >> 4;
  const int wid = (blockIdx.x << 2) + w;
  const int NW = gridDim.x << 2;
  const int NT = gridDim.x * 256;
  const int gtid = blockIdx.x * 256 + t;

  // ---- P0: init hb ----
  for (int idx = gtid; idx < NN * 64; idx += NT) {
    int n = idx >> 6, c = idx & 63;
    hb[idx] = (c < IN_C) ? bf16r(x[n * IN_C + c]) : (ushort)0;
  }
  __threadfence();
  grid.sync();
  __threadfence();

  for (int layer = 0; layer < 2; ++layer) {
    // ---- gemm: m16 = bf16(hb @ Wg[layer]) ----
    {
      const float* WgL = Wg + layer * 64 * 64;
      bf16x8 B[4][2];
#pragma unroll
      for (int ct = 0; ct < 4; ++ct)
#pragma unroll
        for (int kh = 0; kh < 2; ++kh) {
          bf16x8 bb;
#pragma unroll
          for (int j = 0; j < 8; ++j)
            bb[j] = (short)bf16r(WgL[(kh * 32 + quad * 8 + j) * 64 + ct * 16 + cl]);
          B[ct][kh] = bb;
        }
      for (int g = wid; g < NGR; g += NW) {
        const ushort* hp = hb + (size_t)(g * 16 + cl) * 64 + quad * 8;
        bf16x8 a0 = *(const bf16x8*)hp;
        bf16x8 a1 = *(const bf16x8*)(hp + 32);
        ushort* mp = m16 + (size_t)(g * 16 + quad * 4) * 64 + cl;
#pragma unroll
        for (int ct = 0; ct < 4; ++ct) {
          f32x4 acc = {0.0f, 0.0f, 0.0f, 0.0f};
          acc = __builtin_amdgcn_mfma_f32_16x16x32_bf16(a0, B[ct][0], acc, 0, 0, 0);
          acc = __builtin_amdgcn_mfma_f32_16x16x32_bf16(a1, B[ct][1], acc, 0, 0, 0);
#pragma unroll
          for (int rg = 0; rg < 4; ++rg)
            mp[(size_t)rg * 64 + ct * 16] = bf16r(acc[rg]);
        }
      }
    }
    __threadfence();
    grid.sync();
    __threadfence();

    // ---- aggregate: register accumulation, next-node prefetch ----
    {
      int r0c = 0, cC = 0, edc = 0;
      if (wid < NN) {
        r0c = __builtin_amdgcn_readfirstlane(off[wid]);
        cC = __builtin_amdgcn_readfirstlane(cnt[wid]);
        if (lane < cC) edc = csr4[r0c + lane];
      }
      for (int n = wid; n < NN; n += NW) {
        const int c = cC, ed = edc;
        const int n2 = n + NW;
        if (n2 < NN) {
          r0c = __builtin_amdgcn_readfirstlane(off[n2]);
          cC = __builtin_amdgcn_readfirstlane(cnt[n2]);
          edc = 0;
          if (lane < cC) edc = csr4[r0c + lane];
        }
        const int cc = c > 64 ? 64 : c;
        float acc = 0.0f;
        int i = 0;
        for (; i + 8 <= cc; i += 8) {
          int x0 = __builtin_amdgcn_readlane(ed, i + 0);
          int x1 = __builtin_amdgcn_readlane(ed, i + 1);
          int x2 = __builtin_amdgcn_readlane(ed, i + 2);
          int x3 = __builtin_amdgcn_readlane(ed, i + 3);
          int x4 = __builtin_amdgcn_readlane(ed, i + 4);
          int x5 = __builtin_amdgcn_readlane(ed, i + 5);
          int x6 = __builtin_amdgcn_readlane(ed, i + 6);
          int x7 = __builtin_amdgcn_readlane(ed, i + 7);
          float m0 = bf16f(m16[(size_t)(x0 & 0x1FFFF) * 64 + lane]);
          float m1 = bf16f(m16[(size_t)(x1 & 0x1FFFF) * 64 + lane]);
          float m2 = bf16f(m16[(size_t)(x2 & 0x1FFFF) * 64 + lane]);
          float m3 = bf16f(m16[(size_t)(x3 & 0x1FFFF) * 64 + lane]);
          float m4 = bf16f(m16[(size_t)(x4 & 0x1FFFF) * 64 + lane]);
          float m5 = bf16f(m16[(size_t)(x5 & 0x1FFFF) * 64 + lane]);
          float m6 = bf16f(m16[(size_t)(x6 & 0x1FFFF) * 64 + lane]);
          float m7 = bf16f(m16[(size_t)(x7 & 0x1FFFF) * 64 + lane]);
          acc = fmaf(m0, bf16f((ushort)((unsigned)x0 >> 17)), acc);
          acc = fmaf(m1, bf16f((ushort)((unsigned)x1 >> 17)), acc);
          acc = fmaf(m2, bf16f((ushort)((unsigned)x2 >> 17)), acc);
          acc = fmaf(m3, bf16f((ushort)((unsigned)x3 >> 17)), acc);
          acc = fmaf(m4, bf16f((ushort)((unsigned)x4 >> 17)), acc);
          acc = fmaf(m5, bf16f((ushort)((unsigned)x5 >> 17)), acc);
          acc = fmaf(m6, bf16f((ushort)((unsigned)x6 >> 17)), acc);
          acc = fmaf(m7, bf16f((ushort)((unsigned)x7 >> 17)), acc);
        }
        for (; i < cc; ++i) {
          int xx = __builtin_amdgcn_readlane(ed, i);
          acc = fmaf(bf16f(m16[(size_t)(xx & 0x1FFFF) * 64 + lane]),
                     bf16f((ushort)((unsigned)xx >> 17)), acc);
        }
        aggr16[(size_t)n * 64 + lane] = bf16r(acc);
      }
    }
    __threadfence();
    grid.sync();
    __threadfence();

    // ---- gru: block-per-group, MFMA; padded trips keep syncthreads uniform --
    {
      const int c = w * 16 + cl;
      bf16x8 BI[3][2], BH[3][2];
#pragma unroll
      for (int g3 = 0; g3 < 3; ++g3) {
        const float* wi = wih + (size_t)(g3 * 64 + c) * 64;
        const float* wh = whh + (size_t)(g3 * 64 + c) * 64;
#pragma unroll
        for (int kh = 0; kh < 2; ++kh) {
          bf16x8 bi, bh;
#pragma unroll
          for (int j = 0; j < 8; ++j) {
            bi[j] = (short)bf16r(wi[kh * 32 + quad * 8 + j]);
            bh[j] = (short)bf16r(wh[kh * 32 + quad * 8 + j]);
          }
          BI[g3][kh] = bi;
          BH[g3][kh] = bh;
        }
      }
      const float br = bih[c] + bhh[c];
      const float bz = bih[64 + c] + bhh[64 + c];
      const float bni = bih[128 + c];
      const float bnh = bhh[128 + c];
      const int trips = (NGR + gridDim.x - 1) / gridDim.x;
      for (int it = 0; it < trips; ++it) {
        const int g = blockIdx.x + it * gridDim.x;
        const bool act = (g < NGR);
        bf16x8 a0 = {}, a1 = {}, h0 = {}, h1 = {};
        float hv[4] = {0.0f, 0.0f, 0.0f, 0.0f};
        size_t obase = 0;
        if (act) {
          const size_t arow = (size_t)(g * 16 + cl) * 64 + quad * 8;
          a0 = *(const bf16x8*)(aggr16 + arow);
          a1 = *(const bf16x8*)(aggr16 + arow + 32);
          h0 = *(const bf16x8*)(hb + arow);
          h1 = *(const bf16x8*)(hb + arow + 32);
          obase = (size_t)(g * 16 + quad * 4) * 64 + c;
#pragma unroll
          for (int rg = 0; rg < 4; ++rg) hv[rg] = bf16f(hb[obase + (size_t)rg * 64]);
        }
        __syncthreads();  // all h reads before any wave stores h
        if (act) {
          f32x4 zero = {0.0f, 0.0f, 0.0f, 0.0f};
          f32x4 aR = zero, aZ = zero, aN = zero, hR = zero, hZ = zero, hN = zero;
          aR = __builtin_amdgcn_mfma_f32_16x16x32_bf16(a0, BI[0][0], aR, 0, 0, 0);
          aR = __builtin_amdgcn_mfma_f32_16x16x32_bf16(a1, BI[0][1], aR, 0, 0, 0);
          aZ = __builtin_amdgcn_mfma_f32_16x16x32_bf16(a0, BI[1][0], aZ, 0, 0, 0);
          aZ = __builtin_amdgcn_mfma_f32_16x16x32_bf16(a1, BI[1][1], aZ, 0, 0, 0);
          aN = __builtin_amdgcn_mfma_f32_16x16x32_bf16(a0, BI[2][0], aN, 0, 0, 0);
          aN = __builtin_amdgcn_mfma_f32_16x16x32_bf16(a1, BI[2][1], aN, 0, 0, 0);
          hR = __builtin_amdgcn_mfma_f32_16x16x32_bf16(h0, BH[0][0], hR, 0, 0, 0);
          hR = __builtin_amdgcn_mfma_f32_16x16x32_bf16(h1, BH[0][1], hR, 0, 0, 0);
          hZ = __builtin_amdgcn_mfma_f32_16x16x32_bf16(h0, BH[1][0], hZ, 0, 0, 0);
          hZ = __builtin_amdgcn_mfma_f32_16x16x32_bf16(h1, BH[1][1], hZ, 0, 0, 0);
          hN = __builtin_amdgcn_mfma_f32_16x16x32_bf16(h0, BH[2][0], hN, 0, 0, 0);
          hN = __builtin_amdgcn_mfma_f32_16x16x32_bf16(h1, BH[2][1], hN, 0, 0, 0);
#pragma unroll
          for (int rg = 0; rg < 4; ++rg) {
            float r = sigmoidf_(aR[rg] + hR[rg] + br);
            float z = sigmoidf_(aZ[rg] + hZ[rg] + bz);
            float nv = tanhf_(aN[rg] + bni + r * (hN[rg] + bnh));
            hb[obase + (size_t)rg * 64] = bf16r((1.0f - z) * nv + z * hv[rg]);
          }
        }
      }
    }
    __threadfence();
    grid.sync();
    __threadfence();
  }

  // ---- mlp1: grid-stride over 1024 tiles (32 bg x 32 e-slices) ----
  {
    const int c = w * 16 + cl;
    for (int tile = blockIdx.x; tile < 1024; tile += gridDim.x) {
      const int bg = tile >> 5;
      const int sl = tile & 31;
      const int bs0 = bg * 16;
      f32x4 acc = {0.0f, 0.0f, 0.0f, 0.0f};
#pragma unroll
      for (int g = 0; g < 5; ++g) {
        const ushort* hp = hb + ((size_t)(bs0 + cl) * 160 + g * 32 + sl) * 64 + quad * 8;
        bf16x8 a0 = *(const bf16x8*)hp;
        bf16x8 a1 = *(const bf16x8*)(hp + 32);
        const int kbase = sl * 320 + g * 64;
        const ushort* wp = w1b + (size_t)c * KTOT + kbase + quad * 8;
        bf16x8 b0 = *(const bf16x8*)wp;
        bf16x8 b1 = *(const bf16x8*)(wp + 32);
        acc = __builtin_amdgcn_mfma_f32_16x16x32_bf16(a0, b0, acc, 0, 0, 0);
        acc = __builtin_amdgcn_mfma_f32_16x16x32_bf16(a1, b1, acc, 0, 0, 0);
      }
      float* pp = part + ((size_t)sl * BSZ + bs0 + quad * 4) * 64 + c;
#pragma unroll
      for (int rg = 0; rg < 4; ++rg) pp[(size_t)rg * 64] = acc[rg];
    }
  }
  __threadfence();
  grid.sync();
  __threadfence();

  // ---- tail: grid-stride over 128 row-blocks ----
  for (int blk = blockIdx.x; blk < BSZ / 4; blk += gridDim.x) {
    const int bs = blk * 4 + w;
    float zp = 0.0f;
#pragma unroll
    for (int s = 0; s < NSLICE; ++s) zp += part[((size_t)s * BSZ + bs) * 64 + lane];
    float zv = fmaxf(zp + b1[lane], 0.0f);
    const int c2 = lane & 31;
    float acc2 = b2[c2];
#pragma unroll
    for (int k = 0; k < 64; ++k) acc2 = fmaf(bcast(zv, k), W2[c2 * 64 + k], acc2);
    acc2 = fmaxf(acc2, 0.0f);
    const int c3 = lane & 15;
    float acc3 = b3[c3];
#pragma unroll
    for (int k = 0; k < 32; ++k) acc3 = fmaf(bcast(acc2, k), W3[c3 * 32 + k], acc3);
    acc3 = fmaxf(acc3, 0.0f);
    float l0 = b4[0], l1 = b4[1], l2 = b4[2];
#pragma unroll
    for (int k = 0; k < 16; ++k) {
      float v = bcast(acc3, k);
      l0 = fmaf(v, W4[k], l0);
      l1 = fmaf(v, W4[16 + k], l1);
      l2 = fmaf(v, W4[32 + k], l2);
    }
    float mx = fmaxf(l0, fmaxf(l1, l2));
    float e0 = __expf(l0 - mx), e1 = __expf(l1 - mx), e2 = __expf(l2 - mx);
    float inv = 1.0f / (e0 + e1 + e2);
    if (lane == 0) {
      out[bs * 3 + 0] = e0 * inv;
      out[bs * 3 + 1] = e1 * inv;
      out[bs * 3 + 2] = e2 * inv;
    }
  }
}

extern "C" void kernel_launch(void* const* d_in, const int* in_sizes, int n_in,
                              void* d_out, int out_size, void* d_ws, size_t ws_size,
                              hipStream_t stream) {
  const float* x = (const float*)d_in[0];
  const int* ei = (const int*)d_in[1];
  const float* ea = (const float*)d_in[2];
  const float* Wg = (const float*)d_in[3];
  const float* wih = (const float*)d_in[4];
  const float* whh = (const float*)d_in[5];
  const float* bih = (const float*)d_in[6];
  const float* bhh = (const float*)d_in[7];
  const float* W1 = (const float*)d_in[8];
  const float* b1 = (const float*)d_in[9];
  const float* W2 = (const float*)d_in[10];
  const float* b2 = (const float*)d_in[11];
  const float* W3 = (const float*)d_in[12];
  const float* b3 = (const float*)d_in[13];
  const float* W4 = (const float*)d_in[14];
  const float* b4 = (const float*)d_in[15];
  float* out = (float*)d_out;

  // workspace layout
  float* part = (float*)d_ws;                           // NSLICE*BSZ*64 f32
  int* ghist = (int*)(part + (size_t)NSLICE * BSZ * 64);// NCB*NCB
  int* gof = ghist + NCB * NCB;                         // NCB*NCB
  int* tot = gof + NCB * NCB;                           // NCB
  int* cstart = tot + NCB;                              // NCB+1 (pad 324)
  int* off = cstart + 324;                              // NN
  int* cnt = off + NN;                                  // NN
  int* ent4 = cnt + NN;                                 // NE
  int* csr4 = ent4 + NE;                                // NE
  ushort* hb = (ushort*)(csr4 + NE);                    // NN*64
  ushort* m16 = hb + (size_t)NN * 64;                   // NN*64
  ushort* aggr16 = m16 + (size_t)NN * 64;               // NN*64
  ushort* w1b = aggr16 + (size_t)NN * 64;               // KTOT*HC
  unsigned char* dstlo = (unsigned char*)(w1b + (size_t)KTOT * HC);  // NE

  // --- build (separate proven kernels) ---
  k_chist<<<NCB, 256, 0, stream>>>(ei, ghist);
  k_rowscan<<<NCB, NCB, 0, stream>>>(ghist, gof, tot);
  k_cscan2<<<1, NCB, 0, stream>>>(tot, cstart);
  k_cpart<<<NCB, 256, 0, stream>>>(ei, ea, gof, cstart, ent4, dstlo);
  k_sort<<<NCB, 256, 0, stream>>>(ent4, dstlo, cstart, csr4, off, cnt);
  k_cvtw<<<KTOT * HC / 256, 256, 0, stream>>>(W1, w1b);

  // --- fused main: clamp grid to cooperative capacity (deterministic) ---
  int occ = 0;
  hipOccupancyMaxActiveBlocksPerMultiprocessor(&occ, k_main, 256, 0);
  if (occ < 1) occ = 1;
  int gridMain = occ * 256;      // 256 CUs on MI355X
  if (gridMain > 1024) gridMain = 1024;

  void* margs[] = {
      (void*)&hb, (void*)&m16, (void*)&aggr16, (void*)&x,
      (void*)&off, (void*)&cnt, (void*)&csr4,
      (void*)&Wg, (void*)&wih, (void*)&whh, (void*)&bih, (void*)&bhh,
      (void*)&w1b, (void*)&part, (void*)&b1,
      (void*)&W2, (void*)&b2, (void*)&W3, (void*)&b3,
      (void*)&W4, (void*)&b4, (void*)&out};
  hipLaunchCooperativeKernel((const void*)k_main, dim3(gridMain), dim3(256),
                             margs, 0, stream);
}

// Round 14
// 343.895 us; speedup vs baseline: 4.5840x; 4.5840x over previous
//
#include <hip/hip_runtime.h>
#include <cstdint>

#define BSZ 512
#define NG 5
#define NEL 32
#define IN_C 5
#define HC 64
#define NN (BSZ * NG * NEL)   // 81920 nodes
#define NE (NN * 16)          // 1310720 edges
#define NC 3
#define KTOT (NG * NEL * HC)  // 10240
#define NSLICE 16
#define NCB 320               // coarse buckets (256 nodes each, dst>>8)
#define CCHUNK (NE / NCB)     // 4096 edges per build block
#define SORTCAP 5120

typedef __attribute__((ext_vector_type(8))) short bf16x8;
typedef __attribute__((ext_vector_type(4))) float f32x4;

__device__ __forceinline__ float bcast(float v, int l) {
  return __int_as_float(__builtin_amdgcn_readlane(__float_as_int(v), l));
}

__device__ __forceinline__ ushort bf16r(float f) {   // RNE f32->bf16
  unsigned u = __float_as_uint(f);
  return (ushort)((u + 0x7FFFu + ((u >> 16) & 1u)) >> 16);
}

__device__ __forceinline__ float bf16f(ushort s) {
  return __uint_as_float(((unsigned)s) << 16);
}

__device__ __forceinline__ float sigmoidf_(float x) {
  return 1.0f / (1.0f + __expf(-x));
}

__device__ __forceinline__ float tanhf_(float x) {
  x = fminf(fmaxf(x, -15.0f), 15.0f);
  float e = __expf(2.0f * x);
  return (e - 1.0f) / (e + 1.0f);
}

// ---------------- build: hist (+ fused hb-init + W1->bf16) ----------------
__global__ void __launch_bounds__(256) k_chist(const int* __restrict__ ei,
                                               int* __restrict__ ghist,
                                               const float* __restrict__ x,
                                               ushort* __restrict__ hb,
                                               const float* __restrict__ W1,
                                               ushort* __restrict__ w1b) {
  __shared__ int lh[NCB];
  const int t = threadIdx.x;
  for (int i = t; i < NCB; i += 256) lh[i] = 0;
  __syncthreads();
  const int base = blockIdx.x * CCHUNK;
  for (int k = t; k < CCHUNK; k += 256)
    atomicAdd(&lh[ei[NE + base + k] >> 8], 1);
  // fused independent work: hb init + W1 conversion
  const int gtid = blockIdx.x * 256 + t;
  for (int idx = gtid; idx < NN * 64; idx += NCB * 256) {
    int n = idx >> 6, c = idx & 63;
    hb[idx] = (c < IN_C) ? bf16r(x[n * IN_C + c]) : (ushort)0;
  }
  for (int idx = gtid; idx < KTOT * HC; idx += NCB * 256)
    w1b[idx] = bf16r(W1[idx]);
  __syncthreads();
  for (int i = t; i < NCB; i += 256) ghist[i * NCB + blockIdx.x] = lh[i];
}

__global__ void __launch_bounds__(NCB) k_rowscan(const int* __restrict__ ghist,
                                                 int* __restrict__ gof,
                                                 int* __restrict__ tot) {
  __shared__ int part[NCB];
  const int t = threadIdx.x;
  const int b = blockIdx.x;
  const int v = ghist[b * NCB + t];
  part[t] = v;
  __syncthreads();
  for (int d = 1; d < NCB; d <<= 1) {
    int x = (t >= d) ? part[t - d] : 0;
    __syncthreads();
    part[t] += x;
    __syncthreads();
  }
  gof[b * NCB + t] = part[t] - v;
  if (t == NCB - 1) tot[b] = part[t];
}

__global__ void __launch_bounds__(NCB) k_cscan2(const int* __restrict__ tot,
                                                int* __restrict__ cstart) {
  __shared__ int part[NCB];
  const int t = threadIdx.x;
  const int v = tot[t];
  part[t] = v;
  __syncthreads();
  for (int d = 1; d < NCB; d <<= 1) {
    int x = (t >= d) ? part[t - d] : 0;
    __syncthreads();
    part[t] += x;
    __syncthreads();
  }
  cstart[t] = part[t] - v;
  if (t == NCB - 1) cstart[NCB] = part[t];
}

__global__ void __launch_bounds__(256) k_cpart(const int* __restrict__ ei,
                                               const float* __restrict__ ea,
                                               const int* __restrict__ gof,
                                               const int* __restrict__ cstart,
                                               int* __restrict__ ent4,
                                               unsigned char* __restrict__ dstlo) {
  __shared__ int cur[NCB];
  const int t = threadIdx.x;
  for (int i = t; i < NCB; i += 256)
    cur[i] = gof[i * NCB + blockIdx.x] + cstart[i];
  __syncthreads();
  const int base = blockIdx.x * CCHUNK;
  for (int k = t; k < CCHUNK; k += 256) {
    int e = base + k;
    int src = ei[e];
    int dst = ei[NE + e];
    ushort bw = bf16r(ea[e]);       // w in [0,1): bit15==0, fits bits 17..31
    int slot = atomicAdd(&cur[dst >> 8], 1);
    ent4[slot] = src | ((int)bw << 17);
    dstlo[slot] = (unsigned char)(dst & 255);
  }
}

__global__ void __launch_bounds__(256) k_sort(const int* __restrict__ ent4,
                                              const unsigned char* __restrict__ dstlo,
                                              const int* __restrict__ cstart,
                                              int* __restrict__ csr4,
                                              int* __restrict__ off,
                                              int* __restrict__ cnt) {
  __shared__ int nh[256];
  __shared__ int part[256];
  __shared__ int sent[SORTCAP];
  const int t = threadIdx.x;
  const int b = blockIdx.x;
  const int r0 = cstart[b];
  const int r1 = cstart[b + 1];
  int len = r1 - r0;
  if (len > SORTCAP) len = SORTCAP;
  nh[t] = 0;
  __syncthreads();
  for (int k = t; k < len; k += 256) atomicAdd(&nh[dstlo[r0 + k]], 1);
  __syncthreads();
  int a0 = nh[t];
  part[t] = a0;
  __syncthreads();
  for (int d = 1; d < 256; d <<= 1) {
    int x = (t >= d) ? part[t - d] : 0;
    __syncthreads();
    part[t] += x;
    __syncthreads();
  }
  const int base = part[t] - a0;
  const int n0 = b * 256;
  off[n0 + t] = r0 + base;
  cnt[n0 + t] = a0;
  nh[t] = base;
  __syncthreads();
  for (int k = t; k < len; k += 256) {
    int d = dstlo[r0 + k];
    int slot = atomicAdd(&nh[d], 1);
    sent[slot] = ent4[r0 + k];
  }
  __syncthreads();
  for (int k = t; k < len; k += 256) csr4[r0 + k] = sent[k];
}

// ---------------- per-layer kernels ----------------

__global__ void __launch_bounds__(256) k_gemm_mfma(
    const ushort* __restrict__ hb, const float* __restrict__ Wg,
    ushort* __restrict__ m16) {
  const int lane = threadIdx.x & 63;
  const int cl = lane & 15;
  const int quad = lane >> 4;
  bf16x8 B[4][2];
#pragma unroll
  for (int ct = 0; ct < 4; ++ct)
#pragma unroll
    for (int kh = 0; kh < 2; ++kh) {
      bf16x8 b;
#pragma unroll
      for (int j = 0; j < 8; ++j)
        b[j] = (short)bf16r(Wg[(kh * 32 + quad * 8 + j) * 64 + ct * 16 + cl]);
      B[ct][kh] = b;
    }
  int g = (blockIdx.x * 256 + threadIdx.x) >> 6;
  const int nwaves = (gridDim.x * 256) >> 6;
  for (; g < NN / 16; g += nwaves) {
    const ushort* hp = hb + (size_t)(g * 16 + cl) * 64 + quad * 8;
    bf16x8 a0 = *(const bf16x8*)hp;
    bf16x8 a1 = *(const bf16x8*)(hp + 32);
    ushort* mp = m16 + (size_t)(g * 16 + quad * 4) * 64 + cl;
#pragma unroll
    for (int ct = 0; ct < 4; ++ct) {
      f32x4 acc = {0.0f, 0.0f, 0.0f, 0.0f};
      acc = __builtin_amdgcn_mfma_f32_16x16x32_bf16(a0, B[ct][0], acc, 0, 0, 0);
      acc = __builtin_amdgcn_mfma_f32_16x16x32_bf16(a1, B[ct][1], acc, 0, 0, 0);
#pragma unroll
      for (int rg = 0; rg < 4; ++rg)
        mp[(size_t)rg * 64 + ct * 16] = bf16r(acc[rg]);
    }
  }
}

// aggr16[n] = bf16( sum over sorted row n of m16[src]*w ); register acc,
// next-node descriptor prefetch, 16-wide gather batches.
__global__ void k_aggregate(const int* __restrict__ off, const int* __restrict__ cnt,
                            const int* __restrict__ csr4, const ushort* __restrict__ m16,
                            ushort* __restrict__ aggr16) {
  const int lane = threadIdx.x & 63;
  int wv = (blockIdx.x * 256 + threadIdx.x) >> 6;
  const int nw = (gridDim.x * 256) >> 6;
  int r0c = 0, cC = 0, edc = 0;
  if (wv < NN) {
    r0c = __builtin_amdgcn_readfirstlane(off[wv]);
    cC = __builtin_amdgcn_readfirstlane(cnt[wv]);
    if (lane < cC) edc = csr4[r0c + lane];
  }
  for (int n = wv; n < NN; n += nw) {
    const int r0 = r0c, c = cC, ed = edc;
    const int n2 = n + nw;
    if (n2 < NN) {
      r0c = __builtin_amdgcn_readfirstlane(off[n2]);
      cC = __builtin_amdgcn_readfirstlane(cnt[n2]);
      edc = 0;
      if (lane < cC) edc = csr4[r0c + lane];
    }
    const int cc = c > 64 ? 64 : c;
    float acc = 0.0f;
    int i = 0;
    for (; i + 16 <= cc; i += 16) {
      float mv[16], wvv[16];
#pragma unroll
      for (int j = 0; j < 16; ++j) {
        int xx = __builtin_amdgcn_readlane(ed, i + j);
        mv[j] = bf16f(m16[(size_t)(xx & 0x1FFFF) * 64 + lane]);
        wvv[j] = bf16f((ushort)((unsigned)xx >> 17));
      }
#pragma unroll
      for (int j = 0; j < 16; ++j) acc = fmaf(mv[j], wvv[j], acc);
    }
    for (; i + 8 <= cc; i += 8) {
      float mv[8], wvv[8];
#pragma unroll
      for (int j = 0; j < 8; ++j) {
        int xx = __builtin_amdgcn_readlane(ed, i + j);
        mv[j] = bf16f(m16[(size_t)(xx & 0x1FFFF) * 64 + lane]);
        wvv[j] = bf16f((ushort)((unsigned)xx >> 17));
      }
#pragma unroll
      for (int j = 0; j < 8; ++j) acc = fmaf(mv[j], wvv[j], acc);
    }
    for (; i < cc; ++i) {
      int xx = __builtin_amdgcn_readlane(ed, i);
      acc = fmaf(bf16f(m16[(size_t)(xx & 0x1FFFF) * 64 + lane]),
                 bf16f((ushort)((unsigned)xx >> 17)), acc);
    }
    for (int j = 64; j < c; ++j) {  // statistically impossible (row > 64)
      int xx = csr4[r0 + j];
      acc = fmaf(bf16f(m16[(size_t)(xx & 0x1FFFF) * 64 + lane]),
                 bf16f((ushort)((unsigned)xx >> 17)), acc);
    }
    aggr16[(size_t)n * 64 + lane] = bf16r(acc);
  }
}

// GRU via MFMA: gi = aggr@wih.T, gh = h@whh.T, gates, h update (bf16 h).
__global__ void __launch_bounds__(256) k_gru_mfma(
    const ushort* __restrict__ aggr16, ushort* __restrict__ hb,
    const float* __restrict__ wih, const float* __restrict__ whh,
    const float* __restrict__ bih, const float* __restrict__ bhh) {
  const int lane = threadIdx.x & 63;
  const int w = threadIdx.x >> 6;
  const int cl = lane & 15;
  const int quad = lane >> 4;
  const int c = w * 16 + cl;

  bf16x8 BI[3][2], BH[3][2];
#pragma unroll
  for (int g3 = 0; g3 < 3; ++g3) {
    const float* wi = wih + (size_t)(g3 * 64 + c) * 64;
    const float* wh = whh + (size_t)(g3 * 64 + c) * 64;
#pragma unroll
    for (int kh = 0; kh < 2; ++kh) {
      bf16x8 bi, bh;
#pragma unroll
      for (int j = 0; j < 8; ++j) {
        bi[j] = (short)bf16r(wi[kh * 32 + quad * 8 + j]);
        bh[j] = (short)bf16r(wh[kh * 32 + quad * 8 + j]);
      }
      BI[g3][kh] = bi;
      BH[g3][kh] = bh;
    }
  }
  const float br = bih[c] + bhh[c];
  const float bz = bih[64 + c] + bhh[64 + c];
  const float bni = bih[128 + c];
  const float bnh = bhh[128 + c];

  const int ngroups = NN / 16;  // 5120
  for (int g = blockIdx.x; g < ngroups; g += gridDim.x) {
    const size_t arow = (size_t)(g * 16 + cl) * 64 + quad * 8;
    bf16x8 a0 = *(const bf16x8*)(aggr16 + arow);
    bf16x8 a1 = *(const bf16x8*)(aggr16 + arow + 32);
    bf16x8 h0 = *(const bf16x8*)(hb + arow);
    bf16x8 h1 = *(const bf16x8*)(hb + arow + 32);
    float hv[4];
    const size_t obase = (size_t)(g * 16 + quad * 4) * 64 + c;
#pragma unroll
    for (int rg = 0; rg < 4; ++rg) hv[rg] = bf16f(hb[obase + (size_t)rg * 64]);
    __syncthreads();  // all h reads before any wave stores h

    f32x4 zero = {0.0f, 0.0f, 0.0f, 0.0f};
    f32x4 aR = zero, aZ = zero, aN = zero, hR = zero, hZ = zero, hN = zero;
    aR = __builtin_amdgcn_mfma_f32_16x16x32_bf16(a0, BI[0][0], aR, 0, 0, 0);
    aR = __builtin_amdgcn_mfma_f32_16x16x32_bf16(a1, BI[0][1], aR, 0, 0, 0);
    aZ = __builtin_amdgcn_mfma_f32_16x16x32_bf16(a0, BI[1][0], aZ, 0, 0, 0);
    aZ = __builtin_amdgcn_mfma_f32_16x16x32_bf16(a1, BI[1][1], aZ, 0, 0, 0);
    aN = __builtin_amdgcn_mfma_f32_16x16x32_bf16(a0, BI[2][0], aN, 0, 0, 0);
    aN = __builtin_amdgcn_mfma_f32_16x16x32_bf16(a1, BI[2][1], aN, 0, 0, 0);
    hR = __builtin_amdgcn_mfma_f32_16x16x32_bf16(h0, BH[0][0], hR, 0, 0, 0);
    hR = __builtin_amdgcn_mfma_f32_16x16x32_bf16(h1, BH[0][1], hR, 0, 0, 0);
    hZ = __builtin_amdgcn_mfma_f32_16x16x32_bf16(h0, BH[1][0], hZ, 0, 0, 0);
    hZ = __builtin_amdgcn_mfma_f32_16x16x32_bf16(h1, BH[1][1], hZ, 0, 0, 0);
    hN = __builtin_amdgcn_mfma_f32_16x16x32_bf16(h0, BH[2][0], hN, 0, 0, 0);
    hN = __builtin_amdgcn_mfma_f32_16x16x32_bf16(h1, BH[2][1], hN, 0, 0, 0);

#pragma unroll
    for (int rg = 0; rg < 4; ++rg) {
      float r = sigmoidf_(aR[rg] + hR[rg] + br);
      float z = sigmoidf_(aZ[rg] + hZ[rg] + bz);
      float nv = tanhf_(aN[rg] + bni + r * (hN[rg] + bnh));
      hb[obase + (size_t)rg * 64] = bf16r((1.0f - z) * nv + z * hv[rg]);
    }
  }
}

// MLP1 via MFMA: part[sl][bs][c] = A-slice @ W1.T-slice (all-bf16 inputs)
__global__ void __launch_bounds__(256) k_mlp1_mfma(
    const ushort* __restrict__ hb, const ushort* __restrict__ w1b,
    float* __restrict__ part) {
  const int lane = threadIdx.x & 63;
  const int w = threadIdx.x >> 6;
  const int cl = lane & 15;
  const int quad = lane >> 4;
  const int bg = blockIdx.x >> 4;
  const int sl = blockIdx.x & 15;
  const int bs0 = bg * 16;
  const int c = w * 16 + cl;
  f32x4 acc = {0.0f, 0.0f, 0.0f, 0.0f};
#pragma unroll
  for (int e2 = 0; e2 < 2; ++e2) {
    const int e = sl * 2 + e2;
#pragma unroll
    for (int g = 0; g < 5; ++g) {
      const ushort* hp = hb + ((size_t)(bs0 + cl) * 160 + g * 32 + e) * 64 + quad * 8;
      bf16x8 a0 = *(const bf16x8*)hp;
      bf16x8 a1 = *(const bf16x8*)(hp + 32);
      const int kbase = e * 320 + g * 64;
      const ushort* wp = w1b + (size_t)c * KTOT + kbase + quad * 8;
      bf16x8 b0 = *(const bf16x8*)wp;
      bf16x8 b1 = *(const bf16x8*)(wp + 32);
      acc = __builtin_amdgcn_mfma_f32_16x16x32_bf16(a0, b0, acc, 0, 0, 0);
      acc = __builtin_amdgcn_mfma_f32_16x16x32_bf16(a1, b1, acc, 0, 0, 0);
    }
  }
  float* pp = part + ((size_t)sl * BSZ + bs0 + quad * 4) * 64 + c;
#pragma unroll
  for (int rg = 0; rg < 4; ++rg) pp[(size_t)rg * 64] = acc[rg];
}

// sum 16 slice-partials, +b1, relu -> 32 -> 16 -> 3 -> softmax; wave-per-row
__global__ void k_tail(const float* __restrict__ part, const float* __restrict__ b1,
                       const float* __restrict__ W2, const float* __restrict__ b2,
                       const float* __restrict__ W3, const float* __restrict__ b3,
                       const float* __restrict__ W4, const float* __restrict__ b4,
                       float* __restrict__ out) {
  const int lane = threadIdx.x & 63;
  const int bs = blockIdx.x * 4 + (threadIdx.x >> 6);
  float zp = 0.0f;
#pragma unroll
  for (int s = 0; s < NSLICE; ++s) zp += part[((size_t)s * BSZ + bs) * 64 + lane];
  float zv = fmaxf(zp + b1[lane], 0.0f);
  const int c2 = lane & 31;
  float acc2 = b2[c2];
#pragma unroll
  for (int k = 0; k < 64; ++k) acc2 = fmaf(bcast(zv, k), W2[c2 * 64 + k], acc2);
  acc2 = fmaxf(acc2, 0.0f);
  const int c3 = lane & 15;
  float acc3 = b3[c3];
#pragma unroll
  for (int k = 0; k < 32; ++k) acc3 = fmaf(bcast(acc2, k), W3[c3 * 32 + k], acc3);
  acc3 = fmaxf(acc3, 0.0f);
  float l0 = b4[0], l1 = b4[1], l2 = b4[2];
#pragma unroll
  for (int k = 0; k < 16; ++k) {
    float v = bcast(acc3, k);
    l0 = fmaf(v, W4[k], l0);
    l1 = fmaf(v, W4[16 + k], l1);
    l2 = fmaf(v, W4[32 + k], l2);
  }
  float mx = fmaxf(l0, fmaxf(l1, l2));
  float e0 = __expf(l0 - mx), e1 = __expf(l1 - mx), e2 = __expf(l2 - mx);
  float inv = 1.0f / (e0 + e1 + e2);
  if (lane == 0) {
    out[bs * 3 + 0] = e0 * inv;
    out[bs * 3 + 1] = e1 * inv;
    out[bs * 3 + 2] = e2 * inv;
  }
}

extern "C" void kernel_launch(void* const* d_in, const int* in_sizes, int n_in,
                              void* d_out, int out_size, void* d_ws, size_t ws_size,
                              hipStream_t stream) {
  const float* x = (const float*)d_in[0];
  const int* ei = (const int*)d_in[1];
  const float* ea = (const float*)d_in[2];
  const float* Wg = (const float*)d_in[3];
  const float* wih = (const float*)d_in[4];
  const float* whh = (const float*)d_in[5];
  const float* bih = (const float*)d_in[6];
  const float* bhh = (const float*)d_in[7];
  const float* W1 = (const float*)d_in[8];
  const float* b1 = (const float*)d_in[9];
  const float* W2 = (const float*)d_in[10];
  const float* b2 = (const float*)d_in[11];
  const float* W3 = (const float*)d_in[12];
  const float* b3 = (const float*)d_in[13];
  const float* W4 = (const float*)d_in[14];
  const float* b4 = (const float*)d_in[15];
  float* out = (float*)d_out;

  // workspace layout
  float* part = (float*)d_ws;                           // NSLICE*BSZ*64 f32
  int* ghist = (int*)(part + (size_t)NSLICE * BSZ * 64);// NCB*NCB
  int* gof = ghist + NCB * NCB;                         // NCB*NCB
  int* tot = gof + NCB * NCB;                           // NCB
  int* cstart = tot + NCB;                              // NCB+1 (pad 324)
  int* off = cstart + 324;                              // NN
  int* cnt = off + NN;                                  // NN
  int* ent4 = cnt + NN;                                 // NE
  int* csr4 = ent4 + NE;                                // NE
  ushort* hb = (ushort*)(csr4 + NE);                    // NN*64
  ushort* m16 = hb + (size_t)NN * 64;                   // NN*64
  ushort* aggr16 = m16 + (size_t)NN * 64;               // NN*64
  ushort* w1b = aggr16 + (size_t)NN * 64;               // KTOT*HC
  unsigned char* dstlo = (unsigned char*)(w1b + (size_t)KTOT * HC);  // NE

  // --- build (hist kernel also does hb-init + W1 conversion) ---
  k_chist<<<NCB, 256, 0, stream>>>(ei, ghist, x, hb, W1, w1b);
  k_rowscan<<<NCB, NCB, 0, stream>>>(ghist, gof, tot);
  k_cscan2<<<1, NCB, 0, stream>>>(tot, cstart);
  k_cpart<<<NCB, 256, 0, stream>>>(ei, ea, gof, cstart, ent4, dstlo);
  k_sort<<<NCB, 256, 0, stream>>>(ent4, dstlo, cstart, csr4, off, cnt);

  for (int layer = 0; layer < 2; ++layer) {
    k_gemm_mfma<<<1280, 256, 0, stream>>>(hb, Wg + layer * 64 * 64, m16);
    k_aggregate<<<2048, 256, 0, stream>>>(off, cnt, csr4, m16, aggr16);
    k_gru_mfma<<<1280, 256, 0, stream>>>(aggr16, hb, wih, whh, bih, bhh);
  }
  k_mlp1_mfma<<<512, 256, 0, stream>>>(hb, w1b, part);
  k_tail<<<BSZ / 4, 256, 0, stream>>>(part, b1, W2, b2, W3, b3, W4, b4, out);
}

// Round 15
// 332.621 us; speedup vs baseline: 4.7393x; 1.0339x over previous
//
#include <hip/hip_runtime.h>
#include <cstdint>

#define BSZ 512
#define NG 5
#define NEL 32
#define IN_C 5
#define HC 64
#define NN (BSZ * NG * NEL)   // 81920 nodes
#define NE (NN * 16)          // 1310720 edges
#define NC 3
#define KTOT (NG * NEL * HC)  // 10240
#define NSLICE 16
#define NCB 320               // coarse buckets (256 nodes each, dst>>8)
#define CCHUNK (NE / NCB)     // 4096 edges per phase-1 block
#define SORTCAP 5120          // phase-2 LDS capacity (avg 4096, sigma~64)

typedef __attribute__((ext_vector_type(8))) short bf16x8;
typedef __attribute__((ext_vector_type(4))) float f32x4;

__device__ __forceinline__ float bcast(float v, int l) {
  return __int_as_float(__builtin_amdgcn_readlane(__float_as_int(v), l));
}

__device__ __forceinline__ ushort bf16r(float f) {   // RNE f32->bf16
  unsigned u = __float_as_uint(f);
  return (ushort)((u + 0x7FFFu + ((u >> 16) & 1u)) >> 16);
}

__device__ __forceinline__ float bf16f(ushort s) {
  return __uint_as_float(((unsigned)s) << 16);
}

__device__ __forceinline__ float sigmoidf_(float x) {
  return 1.0f / (1.0f + __expf(-x));
}

__device__ __forceinline__ float tanhf_(float x) {
  x = fminf(fmaxf(x, -15.0f), 15.0f);
  float e = __expf(2.0f * x);
  return (e - 1.0f) / (e + 1.0f);
}

// hb[n][c] = bf16( c < 5 ? x[n][c] : 0 )
__global__ void k_init(const float* __restrict__ x, ushort* __restrict__ hb) {
  int idx = blockIdx.x * 256 + threadIdx.x;
  int n = idx >> 6, c = idx & 63;
  hb[idx] = (c < IN_C) ? bf16r(x[n * IN_C + c]) : (ushort)0;
}

// W1 -> bf16 (once)
__global__ void k_cvtw(const float* __restrict__ W1, ushort* __restrict__ w1b) {
  int i = blockIdx.x * 256 + threadIdx.x;
  w1b[i] = bf16r(W1[i]);
}

// ---------------- two-phase edge sort (build, once per launch) ----------------
// phase 1a: per-block LDS histogram over NCB coarse buckets (transposed store)
__global__ void __launch_bounds__(256) k_chist(const int* __restrict__ ei,
                                               int* __restrict__ ghist) {
  __shared__ int lh[NCB];
  const int t = threadIdx.x;
  for (int i = t; i < NCB; i += 256) lh[i] = 0;
  __syncthreads();
  const int base = blockIdx.x * CCHUNK;
  for (int k = t; k < CCHUNK; k += 256)
    atomicAdd(&lh[ei[NE + base + k] >> 8], 1);
  __syncthreads();
  for (int i = t; i < NCB; i += 256) ghist[i * NCB + blockIdx.x] = lh[i];
}

// phase 1b-1: per-bucket exclusive prefix over its 320 per-block counts.
__global__ void __launch_bounds__(NCB) k_rowscan(const int* __restrict__ ghist,
                                                 int* __restrict__ gof,
                                                 int* __restrict__ tot) {
  __shared__ int part[NCB];
  const int t = threadIdx.x;
  const int b = blockIdx.x;
  const int v = ghist[b * NCB + t];
  part[t] = v;
  __syncthreads();
  for (int d = 1; d < NCB; d <<= 1) {
    int x = (t >= d) ? part[t - d] : 0;
    __syncthreads();
    part[t] += x;
    __syncthreads();
  }
  gof[b * NCB + t] = part[t] - v;  // exclusive prefix within bucket row
  if (t == NCB - 1) tot[b] = part[t];
}

// phase 1b-2: exclusive scan of 320 bucket totals -> cstart (+ sentinel)
__global__ void __launch_bounds__(NCB) k_cscan2(const int* __restrict__ tot,
                                                int* __restrict__ cstart) {
  __shared__ int part[NCB];
  const int t = threadIdx.x;
  const int v = tot[t];
  part[t] = v;
  __syncthreads();
  for (int d = 1; d < NCB; d <<= 1) {
    int x = (t >= d) ? part[t - d] : 0;
    __syncthreads();
    part[t] += x;
    __syncthreads();
  }
  cstart[t] = part[t] - v;
  if (t == NCB - 1) cstart[NCB] = part[t];
}

// phase 1c: partition via block-local LDS cursors; entry = src | bf16(w)<<17
__global__ void __launch_bounds__(256) k_cpart(const int* __restrict__ ei,
                                               const float* __restrict__ ea,
                                               const int* __restrict__ gof,
                                               const int* __restrict__ cstart,
                                               int* __restrict__ ent4,
                                               unsigned char* __restrict__ dstlo) {
  __shared__ int cur[NCB];
  const int t = threadIdx.x;
  for (int i = t; i < NCB; i += 256)
    cur[i] = gof[i * NCB + blockIdx.x] + cstart[i];
  __syncthreads();
  const int base = blockIdx.x * CCHUNK;
  for (int k = t; k < CCHUNK; k += 256) {
    int e = base + k;
    int src = ei[e];
    int dst = ei[NE + e];
    ushort bw = bf16r(ea[e]);       // w in [0,1): bit15==0, fits bits 17..31
    int slot = atomicAdd(&cur[dst >> 8], 1);
    ent4[slot] = src | ((int)bw << 17);
    dstlo[slot] = (unsigned char)(dst & 255);
  }
}

// phase 2: per-bucket LDS counting sort -> node-sorted csr4 + off/cnt
__global__ void __launch_bounds__(256) k_sort(const int* __restrict__ ent4,
                                              const unsigned char* __restrict__ dstlo,
                                              const int* __restrict__ cstart,
                                              int* __restrict__ csr4,
                                              int* __restrict__ off,
                                              int* __restrict__ cnt) {
  __shared__ int nh[256];
  __shared__ int part[256];
  __shared__ int sent[SORTCAP];
  const int t = threadIdx.x;
  const int b = blockIdx.x;
  const int r0 = cstart[b];
  const int r1 = cstart[b + 1];
  int len = r1 - r0;
  if (len > SORTCAP) len = SORTCAP;   // statistically impossible
  nh[t] = 0;
  __syncthreads();
  for (int k = t; k < len; k += 256) atomicAdd(&nh[dstlo[r0 + k]], 1);
  __syncthreads();
  int a0 = nh[t];
  part[t] = a0;
  __syncthreads();
  for (int d = 1; d < 256; d <<= 1) {
    int x = (t >= d) ? part[t - d] : 0;
    __syncthreads();
    part[t] += x;
    __syncthreads();
  }
  const int base = part[t] - a0;  // exclusive prefix within bucket
  const int n0 = b * 256;
  off[n0 + t] = r0 + base;
  cnt[n0 + t] = a0;
  nh[t] = base;  // cursor
  __syncthreads();
  for (int k = t; k < len; k += 256) {
    int d = dstlo[r0 + k];
    int slot = atomicAdd(&nh[d], 1);
    sent[slot] = ent4[r0 + k];
  }
  __syncthreads();
  for (int k = t; k < len; k += 256) csr4[r0 + k] = sent[k];  // coalesced
}

// ---------------- per-layer kernels ----------------

// m16 = bf16(hb @ Wg) via MFMA; wave-per-16-node-group, B=Wg hoisted to regs
__global__ void __launch_bounds__(256) k_gemm_mfma(
    const ushort* __restrict__ hb, const float* __restrict__ Wg,
    ushort* __restrict__ m16) {
  const int lane = threadIdx.x & 63;
  const int cl = lane & 15;
  const int quad = lane >> 4;
  bf16x8 B[4][2];
#pragma unroll
  for (int ct = 0; ct < 4; ++ct)
#pragma unroll
    for (int kh = 0; kh < 2; ++kh) {
      bf16x8 b;
#pragma unroll
      for (int j = 0; j < 8; ++j)
        b[j] = (short)bf16r(Wg[(kh * 32 + quad * 8 + j) * 64 + ct * 16 + cl]);
      B[ct][kh] = b;
    }
  int g = (blockIdx.x * 256 + threadIdx.x) >> 6;  // wave id = node group
  const int nwaves = (gridDim.x * 256) >> 6;
  for (; g < NN / 16; g += nwaves) {
    const ushort* hp = hb + (size_t)(g * 16 + cl) * 64 + quad * 8;
    bf16x8 a0 = *(const bf16x8*)hp;
    bf16x8 a1 = *(const bf16x8*)(hp + 32);
    ushort* mp = m16 + (size_t)(g * 16 + quad * 4) * 64 + cl;
#pragma unroll
    for (int ct = 0; ct < 4; ++ct) {
      f32x4 acc = {0.0f, 0.0f, 0.0f, 0.0f};
      acc = __builtin_amdgcn_mfma_f32_16x16x32_bf16(a0, B[ct][0], acc, 0, 0, 0);
      acc = __builtin_amdgcn_mfma_f32_16x16x32_bf16(a1, B[ct][1], acc, 0, 0, 0);
#pragma unroll
      for (int rg = 0; rg < 4; ++rg)
        mp[(size_t)rg * 64 + ct * 16] = bf16r(acc[rg]);
    }
  }
}

// aggr16[n] = bf16( sum over sorted row n of m16[src]*w ); register accumulation,
// next-node descriptor prefetch for latency overlap.
__global__ void k_aggregate(const int* __restrict__ off, const int* __restrict__ cnt,
                            const int* __restrict__ csr4, const ushort* __restrict__ m16,
                            ushort* __restrict__ aggr16) {
  const int lane = threadIdx.x & 63;
  int wv = (blockIdx.x * 256 + threadIdx.x) >> 6;
  const int nw = (gridDim.x * 256) >> 6;
  int r0c = 0, cC = 0, edc = 0;
  if (wv < NN) {
    r0c = __builtin_amdgcn_readfirstlane(off[wv]);
    cC = __builtin_amdgcn_readfirstlane(cnt[wv]);
    if (lane < cC) edc = csr4[r0c + lane];
  }
  for (int n = wv; n < NN; n += nw) {
    const int r0 = r0c, c = cC, ed = edc;
    const int n2 = n + nw;
    if (n2 < NN) {
      r0c = __builtin_amdgcn_readfirstlane(off[n2]);
      cC = __builtin_amdgcn_readfirstlane(cnt[n2]);
      edc = 0;
      if (lane < cC) edc = csr4[r0c + lane];
    }
    const int cc = c > 64 ? 64 : c;
    float acc = 0.0f;
    int i = 0;
    for (; i + 8 <= cc; i += 8) {
      int x0 = __builtin_amdgcn_readlane(ed, i + 0);
      int x1 = __builtin_amdgcn_readlane(ed, i + 1);
      int x2 = __builtin_amdgcn_readlane(ed, i + 2);
      int x3 = __builtin_amdgcn_readlane(ed, i + 3);
      int x4 = __builtin_amdgcn_readlane(ed, i + 4);
      int x5 = __builtin_amdgcn_readlane(ed, i + 5);
      int x6 = __builtin_amdgcn_readlane(ed, i + 6);
      int x7 = __builtin_amdgcn_readlane(ed, i + 7);
      float m0 = bf16f(m16[(size_t)(x0 & 0x1FFFF) * 64 + lane]);
      float m1 = bf16f(m16[(size_t)(x1 & 0x1FFFF) * 64 + lane]);
      float m2 = bf16f(m16[(size_t)(x2 & 0x1FFFF) * 64 + lane]);
      float m3 = bf16f(m16[(size_t)(x3 & 0x1FFFF) * 64 + lane]);
      float m4 = bf16f(m16[(size_t)(x4 & 0x1FFFF) * 64 + lane]);
      float m5 = bf16f(m16[(size_t)(x5 & 0x1FFFF) * 64 + lane]);
      float m6 = bf16f(m16[(size_t)(x6 & 0x1FFFF) * 64 + lane]);
      float m7 = bf16f(m16[(size_t)(x7 & 0x1FFFF) * 64 + lane]);
      acc = fmaf(m0, bf16f((ushort)((unsigned)x0 >> 17)), acc);
      acc = fmaf(m1, bf16f((ushort)((unsigned)x1 >> 17)), acc);
      acc = fmaf(m2, bf16f((ushort)((unsigned)x2 >> 17)), acc);
      acc = fmaf(m3, bf16f((ushort)((unsigned)x3 >> 17)), acc);
      acc = fmaf(m4, bf16f((ushort)((unsigned)x4 >> 17)), acc);
      acc = fmaf(m5, bf16f((ushort)((unsigned)x5 >> 17)), acc);
      acc = fmaf(m6, bf16f((ushort)((unsigned)x6 >> 17)), acc);
      acc = fmaf(m7, bf16f((ushort)((unsigned)x7 >> 17)), acc);
    }
    for (; i < cc; ++i) {
      int x = __builtin_amdgcn_readlane(ed, i);
      acc = fmaf(bf16f(m16[(size_t)(x & 0x1FFFF) * 64 + lane]),
                 bf16f((ushort)((unsigned)x >> 17)), acc);
    }
    for (int j = 64; j < c; ++j) {  // statistically impossible (row > 64)
      int x = csr4[r0 + j];
      acc = fmaf(bf16f(m16[(size_t)(x & 0x1FFFF) * 64 + lane]),
                 bf16f((ushort)((unsigned)x >> 17)), acc);
    }
    aggr16[(size_t)n * 64 + lane] = bf16r(acc);
  }
}

// GRU via MFMA: gi = aggr@wih.T, gh = h@whh.T, gates, h update (bf16 h).
__global__ void __launch_bounds__(256) k_gru_mfma(
    const ushort* __restrict__ aggr16, ushort* __restrict__ hb,
    const float* __restrict__ wih, const float* __restrict__ whh,
    const float* __restrict__ bih, const float* __restrict__ bhh) {
  const int lane = threadIdx.x & 63;
  const int w = threadIdx.x >> 6;
  const int cl = lane & 15;
  const int quad = lane >> 4;
  const int c = w * 16 + cl;

  bf16x8 BI[3][2], BH[3][2];
#pragma unroll
  for (int g3 = 0; g3 < 3; ++g3) {
    const float* wi = wih + (size_t)(g3 * 64 + c) * 64;
    const float* wh = whh + (size_t)(g3 * 64 + c) * 64;
#pragma unroll
    for (int kh = 0; kh < 2; ++kh) {
      bf16x8 bi, bh;
#pragma unroll
      for (int j = 0; j < 8; ++j) {
        bi[j] = (short)bf16r(wi[kh * 32 + quad * 8 + j]);
        bh[j] = (short)bf16r(wh[kh * 32 + quad * 8 + j]);
      }
      BI[g3][kh] = bi;
      BH[g3][kh] = bh;
    }
  }
  const float br = bih[c] + bhh[c];
  const float bz = bih[64 + c] + bhh[64 + c];
  const float bni = bih[128 + c];
  const float bnh = bhh[128 + c];

  const int ngroups = NN / 16;  // 5120
  for (int g = blockIdx.x; g < ngroups; g += gridDim.x) {
    const size_t arow = (size_t)(g * 16 + cl) * 64 + quad * 8;
    bf16x8 a0 = *(const bf16x8*)(aggr16 + arow);
    bf16x8 a1 = *(const bf16x8*)(aggr16 + arow + 32);
    bf16x8 h0 = *(const bf16x8*)(hb + arow);
    bf16x8 h1 = *(const bf16x8*)(hb + arow + 32);
    float hv[4];
    const size_t obase = (size_t)(g * 16 + quad * 4) * 64 + c;
#pragma unroll
    for (int rg = 0; rg < 4; ++rg) hv[rg] = bf16f(hb[obase + (size_t)rg * 64]);
    __syncthreads();  // all h reads done before any wave stores h

    f32x4 zero = {0.0f, 0.0f, 0.0f, 0.0f};
    f32x4 aR = zero, aZ = zero, aN = zero, hR = zero, hZ = zero, hN = zero;
    aR = __builtin_amdgcn_mfma_f32_16x16x32_bf16(a0, BI[0][0], aR, 0, 0, 0);
    aR = __builtin_amdgcn_mfma_f32_16x16x32_bf16(a1, BI[0][1], aR, 0, 0, 0);
    aZ = __builtin_amdgcn_mfma_f32_16x16x32_bf16(a0, BI[1][0], aZ, 0, 0, 0);
    aZ = __builtin_amdgcn_mfma_f32_16x16x32_bf16(a1, BI[1][1], aZ, 0, 0, 0);
    aN = __builtin_amdgcn_mfma_f32_16x16x32_bf16(a0, BI[2][0], aN, 0, 0, 0);
    aN = __builtin_amdgcn_mfma_f32_16x16x32_bf16(a1, BI[2][1], aN, 0, 0, 0);
    hR = __builtin_amdgcn_mfma_f32_16x16x32_bf16(h0, BH[0][0], hR, 0, 0, 0);
    hR = __builtin_amdgcn_mfma_f32_16x16x32_bf16(h1, BH[0][1], hR, 0, 0, 0);
    hZ = __builtin_amdgcn_mfma_f32_16x16x32_bf16(h0, BH[1][0], hZ, 0, 0, 0);
    hZ = __builtin_amdgcn_mfma_f32_16x16x32_bf16(h1, BH[1][1], hZ, 0, 0, 0);
    hN = __builtin_amdgcn_mfma_f32_16x16x32_bf16(h0, BH[2][0], hN, 0, 0, 0);
    hN = __builtin_amdgcn_mfma_f32_16x16x32_bf16(h1, BH[2][1], hN, 0, 0, 0);

#pragma unroll
    for (int rg = 0; rg < 4; ++rg) {
      float r = sigmoidf_(aR[rg] + hR[rg] + br);
      float z = sigmoidf_(aZ[rg] + hZ[rg] + bz);
      float nv = tanhf_(aN[rg] + bni + r * (hN[rg] + bnh));
      hb[obase + (size_t)rg * 64] = bf16r((1.0f - z) * nv + z * hv[rg]);
    }
  }
}

// MLP1 via MFMA: part[sl][bs][c] = A-slice @ W1.T-slice (all-bf16 inputs)
__global__ void __launch_bounds__(256) k_mlp1_mfma(
    const ushort* __restrict__ hb, const ushort* __restrict__ w1b,
    float* __restrict__ part) {
  const int lane = threadIdx.x & 63;
  const int w = threadIdx.x >> 6;
  const int cl = lane & 15;
  const int quad = lane >> 4;
  const int bg = blockIdx.x >> 4;
  const int sl = blockIdx.x & 15;
  const int bs0 = bg * 16;
  const int c = w * 16 + cl;
  f32x4 acc = {0.0f, 0.0f, 0.0f, 0.0f};
#pragma unroll
  for (int e2 = 0; e2 < 2; ++e2) {
    const int e = sl * 2 + e2;
#pragma unroll
    for (int g = 0; g < 5; ++g) {
      const ushort* hp = hb + ((size_t)(bs0 + cl) * 160 + g * 32 + e) * 64 + quad * 8;
      bf16x8 a0 = *(const bf16x8*)hp;
      bf16x8 a1 = *(const bf16x8*)(hp + 32);
      const int kbase = e * 320 + g * 64;
      const ushort* wp = w1b + (size_t)c * KTOT + kbase + quad * 8;
      bf16x8 b0 = *(const bf16x8*)wp;
      bf16x8 b1 = *(const bf16x8*)(wp + 32);
      acc = __builtin_amdgcn_mfma_f32_16x16x32_bf16(a0, b0, acc, 0, 0, 0);
      acc = __builtin_amdgcn_mfma_f32_16x16x32_bf16(a1, b1, acc, 0, 0, 0);
    }
  }
  float* pp = part + ((size_t)sl * BSZ + bs0 + quad * 4) * 64 + c;
#pragma unroll
  for (int rg = 0; rg < 4; ++rg) pp[(size_t)rg * 64] = acc[rg];
}

// sum 16 slice-partials, +b1, relu -> 32 -> 16 -> 3 -> softmax; wave-per-row
__global__ void k_tail(const float* __restrict__ part, const float* __restrict__ b1,
                       const float* __restrict__ W2, const float* __restrict__ b2,
                       const float* __restrict__ W3, const float* __restrict__ b3,
                       const float* __restrict__ W4, const float* __restrict__ b4,
                       float* __restrict__ out) {
  const int lane = threadIdx.x & 63;
  const int bs = blockIdx.x * 4 + (threadIdx.x >> 6);
  float zp = 0.0f;
#pragma unroll
  for (int s = 0; s < NSLICE; ++s) zp += part[((size_t)s * BSZ + bs) * 64 + lane];
  float zv = fmaxf(zp + b1[lane], 0.0f);
  const int c2 = lane & 31;
  float acc2 = b2[c2];
#pragma unroll
  for (int k = 0; k < 64; ++k) acc2 = fmaf(bcast(zv, k), W2[c2 * 64 + k], acc2);
  acc2 = fmaxf(acc2, 0.0f);
  const int c3 = lane & 15;
  float acc3 = b3[c3];
#pragma unroll
  for (int k = 0; k < 32; ++k) acc3 = fmaf(bcast(acc2, k), W3[c3 * 32 + k], acc3);
  acc3 = fmaxf(acc3, 0.0f);
  float l0 = b4[0], l1 = b4[1], l2 = b4[2];
#pragma unroll
  for (int k = 0; k < 16; ++k) {
    float v = bcast(acc3, k);
    l0 = fmaf(v, W4[k], l0);
    l1 = fmaf(v, W4[16 + k], l1);
    l2 = fmaf(v, W4[32 + k], l2);
  }
  float mx = fmaxf(l0, fmaxf(l1, l2));
  float e0 = __expf(l0 - mx), e1 = __expf(l1 - mx), e2 = __expf(l2 - mx);
  float inv = 1.0f / (e0 + e1 + e2);
  if (lane == 0) {
    out[bs * 3 + 0] = e0 * inv;
    out[bs * 3 + 1] = e1 * inv;
    out[bs * 3 + 2] = e2 * inv;
  }
}

extern "C" void kernel_launch(void* const* d_in, const int* in_sizes, int n_in,
                              void* d_out, int out_size, void* d_ws, size_t ws_size,
                              hipStream_t stream) {
  const float* x = (const float*)d_in[0];
  const int* ei = (const int*)d_in[1];
  const float* ea = (const float*)d_in[2];
  const float* Wg = (const float*)d_in[3];
  const float* wih = (const float*)d_in[4];
  const float* whh = (const float*)d_in[5];
  const float* bih = (const float*)d_in[6];
  const float* bhh = (const float*)d_in[7];
  const float* W1 = (const float*)d_in[8];
  const float* b1 = (const float*)d_in[9];
  const float* W2 = (const float*)d_in[10];
  const float* b2 = (const float*)d_in[11];
  const float* W3 = (const float*)d_in[12];
  const float* b3 = (const float*)d_in[13];
  const float* W4 = (const float*)d_in[14];
  const float* b4 = (const float*)d_in[15];
  float* out = (float*)d_out;

  // workspace layout (descending alignment: f32/int, then ushort, then uchar)
  float* part = (float*)d_ws;                           // NSLICE*BSZ*64 f32
  int* ghist = (int*)(part + (size_t)NSLICE * BSZ * 64);// NCB*NCB
  int* gof = ghist + NCB * NCB;                         // NCB*NCB
  int* tot = gof + NCB * NCB;                           // NCB
  int* cstart = tot + NCB;                              // NCB+1 (pad to 324)
  int* off = cstart + 324;                              // NN
  int* cnt = off + NN;                                  // NN
  int* ent4 = cnt + NN;                                 // NE
  int* csr4 = ent4 + NE;                                // NE
  ushort* hb = (ushort*)(csr4 + NE);                    // NN*64
  ushort* m16 = hb + (size_t)NN * 64;                   // NN*64
  ushort* aggr16 = m16 + (size_t)NN * 64;               // NN*64
  ushort* w1b = aggr16 + (size_t)NN * 64;               // KTOT*HC
  unsigned char* dstlo = (unsigned char*)(w1b + (size_t)KTOT * HC);  // NE

  // --- build: two-phase edge sort + weight conversion (once per launch) ---
  k_chist<<<NCB, 256, 0, stream>>>(ei, ghist);
  k_rowscan<<<NCB, NCB, 0, stream>>>(ghist, gof, tot);
  k_cscan2<<<1, NCB, 0, stream>>>(tot, cstart);
  k_cpart<<<NCB, 256, 0, stream>>>(ei, ea, gof, cstart, ent4, dstlo);
  k_sort<<<NCB, 256, 0, stream>>>(ent4, dstlo, cstart, csr4, off, cnt);
  k_cvtw<<<KTOT * HC / 256, 256, 0, stream>>>(W1, w1b);

  k_init<<<NN * 64 / 256, 256, 0, stream>>>(x, hb);
  for (int layer = 0; layer < 2; ++layer) {
    k_gemm_mfma<<<1280, 256, 0, stream>>>(hb, Wg + layer * 64 * 64, m16);
    k_aggregate<<<2048, 256, 0, stream>>>(off, cnt, csr4, m16, aggr16);
    k_gru_mfma<<<1280, 256, 0, stream>>>(aggr16, hb, wih, whh, bih, bhh);
  }
  k_mlp1_mfma<<<512, 256, 0, stream>>>(hb, w1b, part);
  k_tail<<<BSZ / 4, 256, 0, stream>>>(part, b1, W2, b2, W3, b3, W4, b4, out);
}

// Round 16
// 324.890 us; speedup vs baseline: 4.8521x; 1.0238x over previous
//
#include <hip/hip_runtime.h>
#include <cstdint>

#define BSZ 512
#define NG 5
#define NEL 32
#define IN_C 5
#define HC 64
#define NN (BSZ * NG * NEL)   // 81920 nodes
#define NE (NN * 16)          // 1310720 edges
#define NC 3
#define KTOT (NG * NEL * HC)  // 10240
#define NSLICE 16
#define NCB 320               // coarse buckets (256 nodes each, dst>>8)
#define CCHUNK (NE / NCB)     // 4096 edges per phase-1 block
#define SORTCAP 5120          // phase-2 LDS capacity (avg 4096, sigma~64)

typedef __attribute__((ext_vector_type(8))) short bf16x8;
typedef __attribute__((ext_vector_type(4))) float f32x4;

__device__ __forceinline__ float bcast(float v, int l) {
  return __int_as_float(__builtin_amdgcn_readlane(__float_as_int(v), l));
}

__device__ __forceinline__ ushort bf16r(float f) {   // RNE f32->bf16
  unsigned u = __float_as_uint(f);
  return (ushort)((u + 0x7FFFu + ((u >> 16) & 1u)) >> 16);
}

__device__ __forceinline__ float bf16f(ushort s) {
  return __uint_as_float(((unsigned)s) << 16);
}

__device__ __forceinline__ float sigmoidf_(float x) {
  return 1.0f / (1.0f + __expf(-x));
}

__device__ __forceinline__ float tanhf_(float x) {
  x = fminf(fmaxf(x, -15.0f), 15.0f);
  float e = __expf(2.0f * x);
  return (e - 1.0f) / (e + 1.0f);
}

// hb[n][c] = bf16( c < 5 ? x[n][c] : 0 )
__global__ void k_init(const float* __restrict__ x, ushort* __restrict__ hb) {
  int idx = blockIdx.x * 256 + threadIdx.x;
  int n = idx >> 6, c = idx & 63;
  hb[idx] = (c < IN_C) ? bf16r(x[n * IN_C + c]) : (ushort)0;
}

// W1 -> bf16 (once)
__global__ void k_cvtw(const float* __restrict__ W1, ushort* __restrict__ w1b) {
  int i = blockIdx.x * 256 + threadIdx.x;
  w1b[i] = bf16r(W1[i]);
}

// ---------------- two-phase edge sort (build, once per launch) ----------------
// phase 1a: per-block LDS histogram over NCB coarse buckets (transposed store)
__global__ void __launch_bounds__(256) k_chist(const int* __restrict__ ei,
                                               int* __restrict__ ghist) {
  __shared__ int lh[NCB];
  const int t = threadIdx.x;
  for (int i = t; i < NCB; i += 256) lh[i] = 0;
  __syncthreads();
  const int base = blockIdx.x * CCHUNK;
  for (int k = t; k < CCHUNK; k += 256)
    atomicAdd(&lh[ei[NE + base + k] >> 8], 1);
  __syncthreads();
  for (int i = t; i < NCB; i += 256) ghist[i * NCB + blockIdx.x] = lh[i];
}

// phase 1b-1: per-bucket exclusive prefix over its 320 per-block counts.
__global__ void __launch_bounds__(NCB) k_rowscan(const int* __restrict__ ghist,
                                                 int* __restrict__ gof,
                                                 int* __restrict__ tot) {
  __shared__ int part[NCB];
  const int t = threadIdx.x;
  const int b = blockIdx.x;
  const int v = ghist[b * NCB + t];
  part[t] = v;
  __syncthreads();
  for (int d = 1; d < NCB; d <<= 1) {
    int x = (t >= d) ? part[t - d] : 0;
    __syncthreads();
    part[t] += x;
    __syncthreads();
  }
  gof[b * NCB + t] = part[t] - v;  // exclusive prefix within bucket row
  if (t == NCB - 1) tot[b] = part[t];
}

// phase 1b-2: exclusive scan of 320 bucket totals -> cstart (+ sentinel)
__global__ void __launch_bounds__(NCB) k_cscan2(const int* __restrict__ tot,
                                                int* __restrict__ cstart) {
  __shared__ int part[NCB];
  const int t = threadIdx.x;
  const int v = tot[t];
  part[t] = v;
  __syncthreads();
  for (int d = 1; d < NCB; d <<= 1) {
    int x = (t >= d) ? part[t - d] : 0;
    __syncthreads();
    part[t] += x;
    __syncthreads();
  }
  cstart[t] = part[t] - v;
  if (t == NCB - 1) cstart[NCB] = part[t];
}

// phase 1c: partition with LDS staging -> piecewise-contiguous (coalesced)
// global writes. Edges grouped by bucket in LDS, then written linearly:
// LDS slot k -> global position delta[bucket] + k.
__global__ void __launch_bounds__(256) k_cpart(const int* __restrict__ ei,
                                               const float* __restrict__ ea,
                                               const int* __restrict__ gof,
                                               const int* __restrict__ cstart,
                                               int* __restrict__ ent4,
                                               unsigned char* __restrict__ dstlo) {
  __shared__ int lhist[NCB];
  __shared__ int lcur[NCB];
  __shared__ int delta[NCB];
  __shared__ int sc[256];
  __shared__ int lent[CCHUNK];   // 16 KB staged entries
  __shared__ int lkey[CCHUNK];   // 16 KB staged dst (17 bits)
  const int t = threadIdx.x;
  const int blk = blockIdx.x;
  const int base = blk * CCHUNK;
  for (int i = t; i < NCB; i += 256) lhist[i] = 0;
  __syncthreads();
  // pass A: local histogram by bucket
  for (int k = t; k < CCHUNK; k += 256)
    atomicAdd(&lhist[ei[NE + base + k] >> 8], 1);
  __syncthreads();
  // local exclusive prefix over 320 buckets (2 per thread for t<160)
  int v0 = 0, v1 = 0;
  if (t < 160) { v0 = lhist[2 * t]; v1 = lhist[2 * t + 1]; }
  sc[t] = v0 + v1;
  __syncthreads();
  for (int d = 1; d < 256; d <<= 1) {
    int x = (t >= d) ? sc[t - d] : 0;
    __syncthreads();
    sc[t] += x;
    __syncthreads();
  }
  if (t < 160) {
    int pref = sc[t] - v0 - v1;   // exclusive prefix (local base)
    int i0 = 2 * t, i1 = 2 * t + 1;
    lcur[i0] = pref;
    lcur[i1] = pref + v0;
    delta[i0] = cstart[i0] + gof[i0 * NCB + blk] - pref;
    delta[i1] = cstart[i1] + gof[i1 * NCB + blk] - (pref + v0);
  }
  __syncthreads();
  // pass B: scatter edges into LDS grouped by bucket
  for (int k = t; k < CCHUNK; k += 256) {
    int e = base + k;
    int src = ei[e];
    int dst = ei[NE + e];
    ushort bw = bf16r(ea[e]);     // w in [0,1): bit15==0, fits bits 17..31
    int slot = atomicAdd(&lcur[dst >> 8], 1);
    lent[slot] = src | ((int)bw << 17);
    lkey[slot] = dst;
  }
  __syncthreads();
  // pass C: linear writeout — piecewise-contiguous global addresses
  for (int k = t; k < CCHUNK; k += 256) {
    int d = lkey[k];
    int g = delta[d >> 8] + k;
    ent4[g] = lent[k];
    dstlo[g] = (unsigned char)(d & 255);
  }
}

// phase 2: per-bucket LDS counting sort -> node-sorted csr4 + off/cnt
__global__ void __launch_bounds__(256) k_sort(const int* __restrict__ ent4,
                                              const unsigned char* __restrict__ dstlo,
                                              const int* __restrict__ cstart,
                                              int* __restrict__ csr4,
                                              int* __restrict__ off,
                                              int* __restrict__ cnt) {
  __shared__ int nh[256];
  __shared__ int part[256];
  __shared__ int sent[SORTCAP];
  const int t = threadIdx.x;
  const int b = blockIdx.x;
  const int r0 = cstart[b];
  const int r1 = cstart[b + 1];
  int len = r1 - r0;
  if (len > SORTCAP) len = SORTCAP;   // statistically impossible
  nh[t] = 0;
  __syncthreads();
  for (int k = t; k < len; k += 256) atomicAdd(&nh[dstlo[r0 + k]], 1);
  __syncthreads();
  int a0 = nh[t];
  part[t] = a0;
  __syncthreads();
  for (int d = 1; d < 256; d <<= 1) {
    int x = (t >= d) ? part[t - d] : 0;
    __syncthreads();
    part[t] += x;
    __syncthreads();
  }
  const int base = part[t] - a0;  // exclusive prefix within bucket
  const int n0 = b * 256;
  off[n0 + t] = r0 + base;
  cnt[n0 + t] = a0;
  nh[t] = base;  // cursor
  __syncthreads();
  for (int k = t; k < len; k += 256) {
    int d = dstlo[r0 + k];
    int slot = atomicAdd(&nh[d], 1);
    sent[slot] = ent4[r0 + k];
  }
  __syncthreads();
  for (int k = t; k < len; k += 256) csr4[r0 + k] = sent[k];  // coalesced
}

// ---------------- per-layer kernels ----------------

// m16 = bf16(hb @ Wg) via MFMA; wave-per-16-node-group, B=Wg hoisted to regs
__global__ void __launch_bounds__(256) k_gemm_mfma(
    const ushort* __restrict__ hb, const float* __restrict__ Wg,
    ushort* __restrict__ m16) {
  const int lane = threadIdx.x & 63;
  const int cl = lane & 15;
  const int quad = lane >> 4;
  bf16x8 B[4][2];
#pragma unroll
  for (int ct = 0; ct < 4; ++ct)
#pragma unroll
    for (int kh = 0; kh < 2; ++kh) {
      bf16x8 b;
#pragma unroll
      for (int j = 0; j < 8; ++j)
        b[j] = (short)bf16r(Wg[(kh * 32 + quad * 8 + j) * 64 + ct * 16 + cl]);
      B[ct][kh] = b;
    }
  int g = (blockIdx.x * 256 + threadIdx.x) >> 6;  // wave id = node group
  const int nwaves = (gridDim.x * 256) >> 6;
  for (; g < NN / 16; g += nwaves) {
    const ushort* hp = hb + (size_t)(g * 16 + cl) * 64 + quad * 8;
    bf16x8 a0 = *(const bf16x8*)hp;
    bf16x8 a1 = *(const bf16x8*)(hp + 32);
    ushort* mp = m16 + (size_t)(g * 16 + quad * 4) * 64 + cl;
#pragma unroll
    for (int ct = 0; ct < 4; ++ct) {
      f32x4 acc = {0.0f, 0.0f, 0.0f, 0.0f};
      acc = __builtin_amdgcn_mfma_f32_16x16x32_bf16(a0, B[ct][0], acc, 0, 0, 0);
      acc = __builtin_amdgcn_mfma_f32_16x16x32_bf16(a1, B[ct][1], acc, 0, 0, 0);
#pragma unroll
      for (int rg = 0; rg < 4; ++rg)
        mp[(size_t)rg * 64 + ct * 16] = bf16r(acc[rg]);
    }
  }
}

// aggr16[n] = bf16( sum over sorted row n of m16[src]*w ); register accumulation,
// next-node descriptor prefetch for latency overlap.
__global__ void k_aggregate(const int* __restrict__ off, const int* __restrict__ cnt,
                            const int* __restrict__ csr4, const ushort* __restrict__ m16,
                            ushort* __restrict__ aggr16) {
  const int lane = threadIdx.x & 63;
  int wv = (blockIdx.x * 256 + threadIdx.x) >> 6;
  const int nw = (gridDim.x * 256) >> 6;
  int r0c = 0, cC = 0, edc = 0;
  if (wv < NN) {
    r0c = __builtin_amdgcn_readfirstlane(off[wv]);
    cC = __builtin_amdgcn_readfirstlane(cnt[wv]);
    if (lane < cC) edc = csr4[r0c + lane];
  }
  for (int n = wv; n < NN; n += nw) {
    const int r0 = r0c, c = cC, ed = edc;
    const int n2 = n + nw;
    if (n2 < NN) {
      r0c = __builtin_amdgcn_readfirstlane(off[n2]);
      cC = __builtin_amdgcn_readfirstlane(cnt[n2]);
      edc = 0;
      if (lane < cC) edc = csr4[r0c + lane];
    }
    const int cc = c > 64 ? 64 : c;
    float acc = 0.0f;
    int i = 0;
    for (; i + 8 <= cc; i += 8) {
      int x0 = __builtin_amdgcn_readlane(ed, i + 0);
      int x1 = __builtin_amdgcn_readlane(ed, i + 1);
      int x2 = __builtin_amdgcn_readlane(ed, i + 2);
      int x3 = __builtin_amdgcn_readlane(ed, i + 3);
      int x4 = __builtin_amdgcn_readlane(ed, i + 4);
      int x5 = __builtin_amdgcn_readlane(ed, i + 5);
      int x6 = __builtin_amdgcn_readlane(ed, i + 6);
      int x7 = __builtin_amdgcn_readlane(ed, i + 7);
      float m0 = bf16f(m16[(size_t)(x0 & 0x1FFFF) * 64 + lane]);
      float m1 = bf16f(m16[(size_t)(x1 & 0x1FFFF) * 64 + lane]);
      float m2 = bf16f(m16[(size_t)(x2 & 0x1FFFF) * 64 + lane]);
      float m3 = bf16f(m16[(size_t)(x3 & 0x1FFFF) * 64 + lane]);
      float m4 = bf16f(m16[(size_t)(x4 & 0x1FFFF) * 64 + lane]);
      float m5 = bf16f(m16[(size_t)(x5 & 0x1FFFF) * 64 + lane]);
      float m6 = bf16f(m16[(size_t)(x6 & 0x1FFFF) * 64 + lane]);
      float m7 = bf16f(m16[(size_t)(x7 & 0x1FFFF) * 64 + lane]);
      acc = fmaf(m0, bf16f((ushort)((unsigned)x0 >> 17)), acc);
      acc = fmaf(m1, bf16f((ushort)((unsigned)x1 >> 17)), acc);
      acc = fmaf(m2, bf16f((ushort)((unsigned)x2 >> 17)), acc);
      acc = fmaf(m3, bf16f((ushort)((unsigned)x3 >> 17)), acc);
      acc = fmaf(m4, bf16f((ushort)((unsigned)x4 >> 17)), acc);
      acc = fmaf(m5, bf16f((ushort)((unsigned)x5 >> 17)), acc);
      acc = fmaf(m6, bf16f((ushort)((unsigned)x6 >> 17)), acc);
      acc = fmaf(m7, bf16f((ushort)((unsigned)x7 >> 17)), acc);
    }
    for (; i < cc; ++i) {
      int x = __builtin_amdgcn_readlane(ed, i);
      acc = fmaf(bf16f(m16[(size_t)(x & 0x1FFFF) * 64 + lane]),
                 bf16f((ushort)((unsigned)x >> 17)), acc);
    }
    for (int j = 64; j < c; ++j) {  // statistically impossible (row > 64)
      int x = csr4[r0 + j];
      acc = fmaf(bf16f(m16[(size_t)(x & 0x1FFFF) * 64 + lane]),
                 bf16f((ushort)((unsigned)x >> 17)), acc);
    }
    aggr16[(size_t)n * 64 + lane] = bf16r(acc);
  }
}

// GRU via MFMA: gi = aggr@wih.T, gh = h@whh.T, gates, h update (bf16 h).
__global__ void __launch_bounds__(256) k_gru_mfma(
    const ushort* __restrict__ aggr16, ushort* __restrict__ hb,
    const float* __restrict__ wih, const float* __restrict__ whh,
    const float* __restrict__ bih, const float* __restrict__ bhh) {
  const int lane = threadIdx.x & 63;
  const int w = threadIdx.x >> 6;
  const int cl = lane & 15;
  const int quad = lane >> 4;
  const int c = w * 16 + cl;

  bf16x8 BI[3][2], BH[3][2];
#pragma unroll
  for (int g3 = 0; g3 < 3; ++g3) {
    const float* wi = wih + (size_t)(g3 * 64 + c) * 64;
    const float* wh = whh + (size_t)(g3 * 64 + c) * 64;
#pragma unroll
    for (int kh = 0; kh < 2; ++kh) {
      bf16x8 bi, bh;
#pragma unroll
      for (int j = 0; j < 8; ++j) {
        bi[j] = (short)bf16r(wi[kh * 32 + quad * 8 + j]);
        bh[j] = (short)bf16r(wh[kh * 32 + quad * 8 + j]);
      }
      BI[g3][kh] = bi;
      BH[g3][kh] = bh;
    }
  }
  const float br = bih[c] + bhh[c];
  const float bz = bih[64 + c] + bhh[64 + c];
  const float bni = bih[128 + c];
  const float bnh = bhh[128 + c];

  const int ngroups = NN / 16;  // 5120
  for (int g = blockIdx.x; g < ngroups; g += gridDim.x) {
    const size_t arow = (size_t)(g * 16 + cl) * 64 + quad * 8;
    bf16x8 a0 = *(const bf16x8*)(aggr16 + arow);
    bf16x8 a1 = *(const bf16x8*)(aggr16 + arow + 32);
    bf16x8 h0 = *(const bf16x8*)(hb + arow);
    bf16x8 h1 = *(const bf16x8*)(hb + arow + 32);
    float hv[4];
    const size_t obase = (size_t)(g * 16 + quad * 4) * 64 + c;
#pragma unroll
    for (int rg = 0; rg < 4; ++rg) hv[rg] = bf16f(hb[obase + (size_t)rg * 64]);
    __syncthreads();  // all h reads done before any wave stores h

    f32x4 zero = {0.0f, 0.0f, 0.0f, 0.0f};
    f32x4 aR = zero, aZ = zero, aN = zero, hR = zero, hZ = zero, hN = zero;
    aR = __builtin_amdgcn_mfma_f32_16x16x32_bf16(a0, BI[0][0], aR, 0, 0, 0);
    aR = __builtin_amdgcn_mfma_f32_16x16x32_bf16(a1, BI[0][1], aR, 0, 0, 0);
    aZ = __builtin_amdgcn_mfma_f32_16x16x32_bf16(a0, BI[1][0], aZ, 0, 0, 0);
    aZ = __builtin_amdgcn_mfma_f32_16x16x32_bf16(a1, BI[1][1], aZ, 0, 0, 0);
    aN = __builtin_amdgcn_mfma_f32_16x16x32_bf16(a0, BI[2][0], aN, 0, 0, 0);
    aN = __builtin_amdgcn_mfma_f32_16x16x32_bf16(a1, BI[2][1], aN, 0, 0, 0);
    hR = __builtin_amdgcn_mfma_f32_16x16x32_bf16(h0, BH[0][0], hR, 0, 0, 0);
    hR = __builtin_amdgcn_mfma_f32_16x16x32_bf16(h1, BH[0][1], hR, 0, 0, 0);
    hZ = __builtin_amdgcn_mfma_f32_16x16x32_bf16(h0, BH[1][0], hZ, 0, 0, 0);
    hZ = __builtin_amdgcn_mfma_f32_16x16x32_bf16(h1, BH[1][1], hZ, 0, 0, 0);
    hN = __builtin_amdgcn_mfma_f32_16x16x32_bf16(h0, BH[2][0], hN, 0, 0, 0);
    hN = __builtin_amdgcn_mfma_f32_16x16x32_bf16(h1, BH[2][1], hN, 0, 0, 0);

#pragma unroll
    for (int rg = 0; rg < 4; ++rg) {
      float r = sigmoidf_(aR[rg] + hR[rg] + br);
      float z = sigmoidf_(aZ[rg] + hZ[rg] + bz);
      float nv = tanhf_(aN[rg] + bni + r * (hN[rg] + bnh));
      hb[obase + (size_t)rg * 64] = bf16r((1.0f - z) * nv + z * hv[rg]);
    }
  }
}

// MLP1 via MFMA: part[sl][bs][c] = A-slice @ W1.T-slice (all-bf16 inputs)
__global__ void __launch_bounds__(256) k_mlp1_mfma(
    const ushort* __restrict__ hb, const ushort* __restrict__ w1b,
    float* __restrict__ part) {
  const int lane = threadIdx.x & 63;
  const int w = threadIdx.x >> 6;
  const int cl = lane & 15;
  const int quad = lane >> 4;
  const int bg = blockIdx.x >> 4;
  const int sl = blockIdx.x & 15;
  const int bs0 = bg * 16;
  const int c = w * 16 + cl;
  f32x4 acc = {0.0f, 0.0f, 0.0f, 0.0f};
#pragma unroll
  for (int e2 = 0; e2 < 2; ++e2) {
    const int e = sl * 2 + e2;
#pragma unroll
    for (int g = 0; g < 5; ++g) {
      const ushort* hp = hb + ((size_t)(bs0 + cl) * 160 + g * 32 + e) * 64 + quad * 8;
      bf16x8 a0 = *(const bf16x8*)hp;
      bf16x8 a1 = *(const bf16x8*)(hp + 32);
      const int kbase = e * 320 + g * 64;
      const ushort* wp = w1b + (size_t)c * KTOT + kbase + quad * 8;
      bf16x8 b0 = *(const bf16x8*)wp;
      bf16x8 b1 = *(const bf16x8*)(wp + 32);
      acc = __builtin_amdgcn_mfma_f32_16x16x32_bf16(a0, b0, acc, 0, 0, 0);
      acc = __builtin_amdgcn_mfma_f32_16x16x32_bf16(a1, b1, acc, 0, 0, 0);
    }
  }
  float* pp = part + ((size_t)sl * BSZ + bs0 + quad * 4) * 64 + c;
#pragma unroll
  for (int rg = 0; rg < 4; ++rg) pp[(size_t)rg * 64] = acc[rg];
}

// sum 16 slice-partials, +b1, relu -> 32 -> 16 -> 3 -> softmax; wave-per-row
__global__ void k_tail(const float* __restrict__ part, const float* __restrict__ b1,
                       const float* __restrict__ W2, const float* __restrict__ b2,
                       const float* __restrict__ W3, const float* __restrict__ b3,
                       const float* __restrict__ W4, const float* __restrict__ b4,
                       float* __restrict__ out) {
  const int lane = threadIdx.x & 63;
  const int bs = blockIdx.x * 4 + (threadIdx.x >> 6);
  float zp = 0.0f;
#pragma unroll
  for (int s = 0; s < NSLICE; ++s) zp += part[((size_t)s * BSZ + bs) * 64 + lane];
  float zv = fmaxf(zp + b1[lane], 0.0f);
  const int c2 = lane & 31;
  float acc2 = b2[c2];
#pragma unroll
  for (int k = 0; k < 64; ++k) acc2 = fmaf(bcast(zv, k), W2[c2 * 64 + k], acc2);
  acc2 = fmaxf(acc2, 0.0f);
  const int c3 = lane & 15;
  float acc3 = b3[c3];
#pragma unroll
  for (int k = 0; k < 32; ++k) acc3 = fmaf(bcast(acc2, k), W3[c3 * 32 + k], acc3);
  acc3 = fmaxf(acc3, 0.0f);
  float l0 = b4[0], l1 = b4[1], l2 = b4[2];
#pragma unroll
  for (int k = 0; k < 16; ++k) {
    float v = bcast(acc3, k);
    l0 = fmaf(v, W4[k], l0);
    l1 = fmaf(v, W4[16 + k], l1);
    l2 = fmaf(v, W4[32 + k], l2);
  }
  float mx = fmaxf(l0, fmaxf(l1, l2));
  float e0 = __expf(l0 - mx), e1 = __expf(l1 - mx), e2 = __expf(l2 - mx);
  float inv = 1.0f / (e0 + e1 + e2);
  if (lane == 0) {
    out[bs * 3 + 0] = e0 * inv;
    out[bs * 3 + 1] = e1 * inv;
    out[bs * 3 + 2] = e2 * inv;
  }
}

extern "C" void kernel_launch(void* const* d_in, const int* in_sizes, int n_in,
                              void* d_out, int out_size, void* d_ws, size_t ws_size,
                              hipStream_t stream) {
  const float* x = (const float*)d_in[0];
  const int* ei = (const int*)d_in[1];
  const float* ea = (const float*)d_in[2];
  const float* Wg = (const float*)d_in[3];
  const float* wih = (const float*)d_in[4];
  const float* whh = (const float*)d_in[5];
  const float* bih = (const float*)d_in[6];
  const float* bhh = (const float*)d_in[7];
  const float* W1 = (const float*)d_in[8];
  const float* b1 = (const float*)d_in[9];
  const float* W2 = (const float*)d_in[10];
  const float* b2 = (const float*)d_in[11];
  const float* W3 = (const float*)d_in[12];
  const float* b3 = (const float*)d_in[13];
  const float* W4 = (const float*)d_in[14];
  const float* b4 = (const float*)d_in[15];
  float* out = (float*)d_out;

  // workspace layout (descending alignment: f32/int, then ushort, then uchar)
  float* part = (float*)d_ws;                           // NSLICE*BSZ*64 f32
  int* ghist = (int*)(part + (size_t)NSLICE * BSZ * 64);// NCB*NCB
  int* gof = ghist + NCB * NCB;                         // NCB*NCB
  int* tot = gof + NCB * NCB;                           // NCB
  int* cstart = tot + NCB;                              // NCB+1 (pad to 324)
  int* off = cstart + 324;                              // NN
  int* cnt = off + NN;                                  // NN
  int* ent4 = cnt + NN;                                 // NE
  int* csr4 = ent4 + NE;                                // NE
  ushort* hb = (ushort*)(csr4 + NE);                    // NN*64
  ushort* m16 = hb + (size_t)NN * 64;                   // NN*64
  ushort* aggr16 = m16 + (size_t)NN * 64;               // NN*64
  ushort* w1b = aggr16 + (size_t)NN * 64;               // KTOT*HC
  unsigned char* dstlo = (unsigned char*)(w1b + (size_t)KTOT * HC);  // NE

  // --- build: two-phase edge sort + weight conversion (once per launch) ---
  k_chist<<<NCB, 256, 0, stream>>>(ei, ghist);
  k_rowscan<<<NCB, NCB, 0, stream>>>(ghist, gof, tot);
  k_cscan2<<<1, NCB, 0, stream>>>(tot, cstart);
  k_cpart<<<NCB, 256, 0, stream>>>(ei, ea, gof, cstart, ent4, dstlo);
  k_sort<<<NCB, 256, 0, stream>>>(ent4, dstlo, cstart, csr4, off, cnt);
  k_cvtw<<<KTOT * HC / 256, 256, 0, stream>>>(W1, w1b);

  k_init<<<NN * 64 / 256, 256, 0, stream>>>(x, hb);
  for (int layer = 0; layer < 2; ++layer) {
    k_gemm_mfma<<<1280, 256, 0, stream>>>(hb, Wg + layer * 64 * 64, m16);
    k_aggregate<<<2048, 256, 0, stream>>>(off, cnt, csr4, m16, aggr16);
    k_gru_mfma<<<1280, 256, 0, stream>>>(aggr16, hb, wih, whh, bih, bhh);
  }
  k_mlp1_mfma<<<512, 256, 0, stream>>>(hb, w1b, part);
  k_tail<<<BSZ / 4, 256, 0, stream>>>(part, b1, W2, b2, W3, b3, W4, b4, out);
}